// Round 1
// baseline (778.120 us; speedup 1.0000x reference)
//
#include <hip/hip_runtime.h>

#define SCALE 128
#define GRID_L (SCALE + 3)              // 131
#define GRID_V (GRID_L * GRID_L * GRID_L) // 2,248,091
#define BATCH 16
#define NPTS 32768                      // points per sample

// ---------------------------------------------------------------------------
// Kernel 1: per-axis integer min of floor(scaled coord) over BOTH clouds.
// mins[3] must be pre-initialized to a large positive int (memset 0x7f).
// floor(min(S)) == min(floor(s)) so integer atomicMin is exact.
// ---------------------------------------------------------------------------
__global__ void grid_min_kernel(const float* __restrict__ pc,
                                const float* __restrict__ gc,
                                int* __restrict__ mins,
                                int npts_total /* BATCH*NPTS */) {
    const float s = SCALE * 0.5f;
    int tid = blockIdx.x * blockDim.x + threadIdx.x;
    int stride = gridDim.x * blockDim.x;
    int m0 = 0x7FFFFFFF, m1 = 0x7FFFFFFF, m2 = 0x7FFFFFFF;
    for (int i = tid; i < npts_total; i += stride) {
        float x = pc[3 * i + 0] * s;
        float y = pc[3 * i + 1] * s;
        float z = pc[3 * i + 2] * s;
        m0 = min(m0, (int)floorf(x));
        m1 = min(m1, (int)floorf(y));
        m2 = min(m2, (int)floorf(z));
        x = gc[3 * i + 0] * s;
        y = gc[3 * i + 1] * s;
        z = gc[3 * i + 2] * s;
        m0 = min(m0, (int)floorf(x));
        m1 = min(m1, (int)floorf(y));
        m2 = min(m2, (int)floorf(z));
    }
    // wave-64 reduction
    #pragma unroll
    for (int off = 32; off > 0; off >>= 1) {
        m0 = min(m0, __shfl_down(m0, off));
        m1 = min(m1, __shfl_down(m1, off));
        m2 = min(m2, __shfl_down(m2, off));
    }
    if ((threadIdx.x & 63) == 0) {
        atomicMin(&mins[0], m0);
        atomicMin(&mins[1], m1);
        atomicMin(&mins[2], m2);
    }
}

// ---------------------------------------------------------------------------
// Kernel 2: trilinear scatter of one cloud into its grid.
// grid layout: [BATCH, GRID_V], x-major flat index (ix*L + iy)*L + iz.
// min_corner = mins[d] - 1 (the reference's floor(min)-1).
// ---------------------------------------------------------------------------
__global__ void gridding_scatter_kernel(const float* __restrict__ cloud,
                                        float* __restrict__ grid,
                                        const int* __restrict__ mins) {
    int i = blockIdx.x * blockDim.x + threadIdx.x;
    if (i >= BATCH * NPTS) return;
    int b = i >> 15; // / NPTS

    const float s = SCALE * 0.5f;
    float x = cloud[3 * i + 0] * s;
    float y = cloud[3 * i + 1] * s;
    float z = cloud[3 * i + 2] * s;

    // reference drops "padding" points whose (scaled) coord sum is exactly 0
    if (x + y + z == 0.0f) return;

    int lx = (int)floorf(x);
    int ly = (int)floorf(y);
    int lz = (int)floorf(z);
    float fx = x - (float)lx;
    float fy = y - (float)ly;
    float fz = z - (float)lz;

    int ix = lx - (mins[0] - 1);
    int iy = ly - (mins[1] - 1);
    int iz = lz - (mins[2] - 1);

    float wx0 = 1.0f - fx, wx1 = fx;
    float wy0 = 1.0f - fy, wy1 = fy;
    float wz0 = 1.0f - fz, wz1 = fz;

    float* g = grid + (size_t)b * GRID_V;
    size_t base = ((size_t)ix * GRID_L + iy) * GRID_L + iz;

    atomicAdd(&g[base],                          wx0 * wy0 * wz0);
    atomicAdd(&g[base + 1],                      wx0 * wy0 * wz1);
    atomicAdd(&g[base + GRID_L],                 wx0 * wy1 * wz0);
    atomicAdd(&g[base + GRID_L + 1],             wx0 * wy1 * wz1);
    atomicAdd(&g[base + GRID_L * GRID_L],        wx1 * wy0 * wz0);
    atomicAdd(&g[base + GRID_L * GRID_L + 1],    wx1 * wy0 * wz1);
    atomicAdd(&g[base + GRID_L * GRID_L + GRID_L],     wx1 * wy1 * wz0);
    atomicAdd(&g[base + GRID_L * GRID_L + GRID_L + 1], wx1 * wy1 * wz1);
}

extern "C" void kernel_launch(void* const* d_in, const int* in_sizes, int n_in,
                              void* d_out, int out_size, void* d_ws, size_t ws_size,
                              hipStream_t stream) {
    const float* pred = (const float*)d_in[0];
    const float* gt   = (const float*)d_in[1];
    float* out = (float*)d_out; // [2, BATCH, GRID_V]: pred_grid then gt_grid
    int* mins = (int*)d_ws;

    // init: mins -> large positive int; output grids -> 0
    hipMemsetAsync(mins, 0x7f, 3 * sizeof(int), stream);
    hipMemsetAsync(out, 0, (size_t)out_size * sizeof(float), stream);

    const int npts_total = BATCH * NPTS; // 524288
    grid_min_kernel<<<256, 256, 0, stream>>>(pred, gt, mins, npts_total);

    const int threads = 256;
    const int blocks = (npts_total + threads - 1) / threads;
    float* pred_grid = out;
    float* gt_grid   = out + (size_t)BATCH * GRID_V;
    gridding_scatter_kernel<<<blocks, threads, 0, stream>>>(pred, pred_grid, mins);
    gridding_scatter_kernel<<<blocks, threads, 0, stream>>>(gt,   gt_grid,   mins);
}

// Round 2
// 544.470 us; speedup vs baseline: 1.4291x; 1.4291x over previous
//
#include <hip/hip_runtime.h>

#define SCALE 128
#define GRID_L 131                      // grid side
#define SLAB (GRID_L * GRID_L)          // 17161 floats per x-slab
#define GRID_V (GRID_L * GRID_L * GRID_L)
#define BATCH 16
#define NPTS 32768                      // points per sample (2^15)
#define NCB 32                          // 2 clouds x 16 samples
#define NBINS 132                       // x-slab bins (used: 1..128)

// ---------------------------------------------------------------------------
// Kernel 1: per-axis integer min of floor(scaled coord) over BOTH clouds.
// mins[3] pre-initialized to 0x7f7f7f7f. floor(min) == min(floor) so integer
// atomicMin is exact.
// ---------------------------------------------------------------------------
__global__ void grid_min_kernel(const float* __restrict__ pc,
                                const float* __restrict__ gc,
                                int* __restrict__ mins) {
    const float s = SCALE * 0.5f;
    int tid = blockIdx.x * blockDim.x + threadIdx.x;
    int stride = gridDim.x * blockDim.x;
    int m0 = 0x7FFFFFFF, m1 = 0x7FFFFFFF, m2 = 0x7FFFFFFF;
    for (int i = tid; i < BATCH * NPTS; i += stride) {
        m0 = min(m0, (int)floorf(pc[3 * i + 0] * s));
        m1 = min(m1, (int)floorf(pc[3 * i + 1] * s));
        m2 = min(m2, (int)floorf(pc[3 * i + 2] * s));
        m0 = min(m0, (int)floorf(gc[3 * i + 0] * s));
        m1 = min(m1, (int)floorf(gc[3 * i + 1] * s));
        m2 = min(m2, (int)floorf(gc[3 * i + 2] * s));
    }
    #pragma unroll
    for (int off = 32; off > 0; off >>= 1) {
        m0 = min(m0, __shfl_down(m0, off));
        m1 = min(m1, __shfl_down(m1, off));
        m2 = min(m2, __shfl_down(m2, off));
    }
    if ((threadIdx.x & 63) == 0) {
        atomicMin(&mins[0], m0);
        atomicMin(&mins[1], m1);
        atomicMin(&mins[2], m2);
    }
}

// ---------------------------------------------------------------------------
// Kernel 2: histogram of points into x-slab bins, per (cloud,sample).
// i in [0, 2*BATCH*NPTS): first half = pred, second half = gt. cb = i>>15.
// ---------------------------------------------------------------------------
__global__ void hist_kernel(const float* __restrict__ pc,
                            const float* __restrict__ gc,
                            const int* __restrict__ mins,
                            int* __restrict__ counts) {
    int i = blockIdx.x * blockDim.x + threadIdx.x;
    if (i >= 2 * BATCH * NPTS) return;
    const float s = SCALE * 0.5f;
    const float* src = (i < BATCH * NPTS) ? pc : gc;
    int j = (i < BATCH * NPTS) ? i : i - BATCH * NPTS;
    float x = src[3 * j + 0] * s;
    float y = src[3 * j + 1] * s;
    float z = src[3 * j + 2] * s;
    if (x + y + z == 0.0f) return;          // padding-point mask
    int px = (int)floorf(x) - (mins[0] - 1);
    int cb = i >> 15;
    atomicAdd(&counts[cb * NBINS + px], 1);
}

// ---------------------------------------------------------------------------
// Kernel 3: per-(cloud,sample) exclusive prefix sum over 132 bins.
// starts has stride NBINS+1 (end sentinel). cursor = mutable copy of starts.
// ---------------------------------------------------------------------------
__global__ void scan_kernel(const int* __restrict__ counts,
                            int* __restrict__ starts,
                            int* __restrict__ cursor) {
    int cb = threadIdx.x;
    if (cb >= NCB) return;
    int acc = 0;
    for (int bin = 0; bin < NBINS; ++bin) {
        starts[cb * (NBINS + 1) + bin] = acc;
        cursor[cb * NBINS + bin] = acc;
        acc += counts[cb * NBINS + bin];
    }
    starts[cb * (NBINS + 1) + NBINS] = acc;
}

// ---------------------------------------------------------------------------
// Kernel 4: reorder points into bin-sorted payloads:
// float4(fx, fy, fz, bits(py | pz<<16)) at sorted[cb*NPTS + slot].
// ---------------------------------------------------------------------------
__global__ void reorder_kernel(const float* __restrict__ pc,
                               const float* __restrict__ gc,
                               const int* __restrict__ mins,
                               int* __restrict__ cursor,
                               float4* __restrict__ sorted) {
    int i = blockIdx.x * blockDim.x + threadIdx.x;
    if (i >= 2 * BATCH * NPTS) return;
    const float s = SCALE * 0.5f;
    const float* src = (i < BATCH * NPTS) ? pc : gc;
    int j = (i < BATCH * NPTS) ? i : i - BATCH * NPTS;
    float x = src[3 * j + 0] * s;
    float y = src[3 * j + 1] * s;
    float z = src[3 * j + 2] * s;
    if (x + y + z == 0.0f) return;
    int lx = (int)floorf(x), ly = (int)floorf(y), lz = (int)floorf(z);
    float fx = x - (float)lx, fy = y - (float)ly, fz = z - (float)lz;
    int px = lx - (mins[0] - 1);
    int py = ly - (mins[1] - 1);
    int pz = lz - (mins[2] - 1);
    int cb = i >> 15;
    int slot = atomicAdd(&cursor[cb * NBINS + px], 1);
    sorted[cb * NPTS + slot] =
        make_float4(fx, fy, fz, __int_as_float(py | (pz << 16)));
}

// ---------------------------------------------------------------------------
// Kernel 5: gather. One block per (cb, ix): accumulate the 131x131 slab in
// LDS from bins ix-1 (upper-corner pts, wx=fx) and ix (lower-corner, wx=1-fx),
// then stream the slab to global exactly once (zeros included -> no memset).
// ---------------------------------------------------------------------------
__global__ void __launch_bounds__(256)
gather_kernel(const float4* __restrict__ sorted,
              const int* __restrict__ starts,
              float* __restrict__ out) {
    __shared__ float tile[SLAB];
    int blk = blockIdx.x;
    int cb = blk / GRID_L;
    int ix = blk - cb * GRID_L;

    for (int t = threadIdx.x; t < SLAB; t += 256) tile[t] = 0.0f;
    __syncthreads();

    const float4* pts = sorted + (size_t)cb * NPTS;
    const int* st = starts + cb * (NBINS + 1);

    #pragma unroll
    for (int pass = 0; pass < 2; ++pass) {
        int bin = ix - 1 + pass;
        if (bin < 0 || bin >= NBINS) continue;
        int b0 = st[bin], b1 = st[bin + 1];
        for (int p = b0 + (int)threadIdx.x; p < b1; p += 256) {
            float4 q = pts[p];
            int pack = __float_as_int(q.w);
            int py = pack & 0xffff;
            int pz = pack >> 16;
            float wx = pass ? (1.0f - q.x) : q.x;
            float wy0 = 1.0f - q.y, wy1 = q.y;
            float wz0 = 1.0f - q.z, wz1 = q.z;
            float* t0 = &tile[py * GRID_L + pz];
            atomicAdd(t0,              wx * wy0 * wz0);
            atomicAdd(t0 + 1,          wx * wy0 * wz1);
            atomicAdd(t0 + GRID_L,     wx * wy1 * wz0);
            atomicAdd(t0 + GRID_L + 1, wx * wy1 * wz1);
        }
    }
    __syncthreads();

    float* o = out + (size_t)cb * GRID_V + (size_t)ix * SLAB;
    for (int t = threadIdx.x; t < SLAB; t += 256) o[t] = tile[t];
}

extern "C" void kernel_launch(void* const* d_in, const int* in_sizes, int n_in,
                              void* d_out, int out_size, void* d_ws, size_t ws_size,
                              hipStream_t stream) {
    const float* pred = (const float*)d_in[0];
    const float* gt   = (const float*)d_in[1];
    float* out = (float*)d_out;   // [2, BATCH, GRID_V]: pred grids then gt grids

    // workspace layout
    char* w = (char*)d_ws;
    int* mins   = (int*)w;                         // 3 ints
    int* counts = (int*)(w + 16);                  // NCB*NBINS
    int* starts = counts + NCB * NBINS;            // NCB*(NBINS+1)
    int* cursor = starts + NCB * (NBINS + 1);      // NCB*NBINS
    size_t off = 16 + sizeof(int) * (size_t)(NCB * NBINS + NCB * (NBINS + 1) + NCB * NBINS);
    off = (off + 15) & ~(size_t)15;
    float4* sorted = (float4*)(w + off);           // NCB*NPTS float4 = 16 MB

    hipMemsetAsync(mins, 0x7f, 3 * sizeof(int), stream);
    hipMemsetAsync(counts, 0, sizeof(int) * NCB * NBINS, stream);

    grid_min_kernel<<<256, 256, 0, stream>>>(pred, gt, mins);

    const int total2 = 2 * BATCH * NPTS;           // 1,048,576
    hist_kernel<<<(total2 + 255) / 256, 256, 0, stream>>>(pred, gt, mins, counts);
    scan_kernel<<<1, 64, 0, stream>>>(counts, starts, cursor);
    reorder_kernel<<<(total2 + 255) / 256, 256, 0, stream>>>(pred, gt, mins, cursor, sorted);
    gather_kernel<<<NCB * GRID_L, 256, 0, stream>>>(sorted, starts, out);
}

// Round 3
// 431.393 us; speedup vs baseline: 1.8037x; 1.2621x over previous
//
#include <hip/hip_runtime.h>

#define SCALE 128
#define GRID_L 131                        // grid side
#define SLAB (GRID_L * GRID_L)            // 17161 floats per x-slab
#define GRID_V (GRID_L * GRID_L * GRID_L)
#define BATCH 16
#define NPTS 32768                        // points per sample (2^15)
#define NCB 32                            // 2 clouds x 16 samples
#define NBINS 132                         // abs x-bin storage stride (used: 0..128)

// ---------------------------------------------------------------------------
// Kernel 1: fused per-axis min + x-histogram in ABSOLUTE bins.
// Absolute bin: floor(x*64) + 64 in [0,128] -- independent of mins, so the
// hist/scan/reorder chain has no dependency on the min reduction.
// 1024 threads/block, one (cloud,sample) per block (1024 | 32768).
// mins[3] pre-set to 0x7f7f7f7f; counts pre-set to 0.
// ---------------------------------------------------------------------------
__global__ void __launch_bounds__(1024)
min_hist_kernel(const float* __restrict__ pc,
                const float* __restrict__ gc,
                int* __restrict__ mins,
                int* __restrict__ counts) {
    __shared__ int h[NBINS];
    __shared__ int red[3 * 16];           // per-wave mins, 16 waves

    for (int t = threadIdx.x; t < NBINS; t += 1024) h[t] = 0;
    __syncthreads();

    int i = blockIdx.x * 1024 + threadIdx.x;       // i in [0, 2*BATCH*NPTS)
    const float s = SCALE * 0.5f;
    const float* src = (i < BATCH * NPTS) ? pc : gc;
    int j = (i < BATCH * NPTS) ? i : i - BATCH * NPTS;
    float x = src[3 * j + 0] * s;
    float y = src[3 * j + 1] * s;
    float z = src[3 * j + 2] * s;
    int lx = (int)floorf(x);
    int ly = (int)floorf(y);
    int lz = (int)floorf(z);

    // histogram (padding points masked; mins include ALL points, per reference)
    if (x + y + z != 0.0f) atomicAdd(&h[lx + 64], 1);

    // wave-64 min reduction
    int m0 = lx, m1 = ly, m2 = lz;
    #pragma unroll
    for (int off = 32; off > 0; off >>= 1) {
        m0 = min(m0, __shfl_down(m0, off));
        m1 = min(m1, __shfl_down(m1, off));
        m2 = min(m2, __shfl_down(m2, off));
    }
    int wave = threadIdx.x >> 6;
    if ((threadIdx.x & 63) == 0) {
        red[3 * wave + 0] = m0;
        red[3 * wave + 1] = m1;
        red[3 * wave + 2] = m2;
    }
    __syncthreads();

    if (threadIdx.x < 3) {
        int m = red[threadIdx.x];
        #pragma unroll
        for (int w = 1; w < 16; ++w) m = min(m, red[3 * w + threadIdx.x]);
        atomicMin(&mins[threadIdx.x], m);
    }

    // flush histogram
    int cb = blockIdx.x >> 5;             // 32 blocks per (cloud,sample)
    for (int t = threadIdx.x; t < NBINS; t += 1024) {
        int c = h[t];
        if (c) atomicAdd(&counts[cb * NBINS + t], c);
    }
}

// ---------------------------------------------------------------------------
// Kernel 2: per-(cloud,sample) exclusive prefix sum over NBINS abs bins.
// ---------------------------------------------------------------------------
__global__ void scan_kernel(const int* __restrict__ counts,
                            int* __restrict__ starts,
                            int* __restrict__ cursor) {
    int cb = threadIdx.x;
    if (cb >= NCB) return;
    int acc = 0;
    for (int bin = 0; bin < NBINS; ++bin) {
        starts[cb * (NBINS + 1) + bin] = acc;
        cursor[cb * NBINS + bin] = acc;
        acc += counts[cb * NBINS + bin];
    }
    starts[cb * (NBINS + 1) + NBINS] = acc;
}

// ---------------------------------------------------------------------------
// Kernel 3: reorder points into abs-bin-sorted payloads (no mins needed):
// float4(fx, fy, fz, bits((ly+64) | (lz+64)<<16)) at sorted[cb*NPTS + slot].
// ---------------------------------------------------------------------------
__global__ void reorder_kernel(const float* __restrict__ pc,
                               const float* __restrict__ gc,
                               int* __restrict__ cursor,
                               float4* __restrict__ sorted) {
    int i = blockIdx.x * blockDim.x + threadIdx.x;
    if (i >= 2 * BATCH * NPTS) return;
    const float s = SCALE * 0.5f;
    const float* src = (i < BATCH * NPTS) ? pc : gc;
    int j = (i < BATCH * NPTS) ? i : i - BATCH * NPTS;
    float x = src[3 * j + 0] * s;
    float y = src[3 * j + 1] * s;
    float z = src[3 * j + 2] * s;
    if (x + y + z == 0.0f) return;
    int lx = (int)floorf(x), ly = (int)floorf(y), lz = (int)floorf(z);
    float fx = x - (float)lx, fy = y - (float)ly, fz = z - (float)lz;
    int cb = i >> 15;
    int slot = atomicAdd(&cursor[cb * NBINS + (lx + 64)], 1);
    sorted[cb * NPTS + slot] =
        make_float4(fx, fy, fz, __int_as_float((ly + 64) | ((lz + 64) << 16)));
}

// ---------------------------------------------------------------------------
// Kernel 4: gather. One 1024-thread block per (cb, ix): accumulate the
// 131x131 slab in LDS from abs bins (ix-2+minoffx) [w=fx] and (ix-1+minoffx)
// [w=1-fx], then stream the slab out exactly once (nontemporal; no memset).
// 68.6 KB LDS -> 2 blocks/CU -> 32 waves/CU.
// ---------------------------------------------------------------------------
__global__ void __launch_bounds__(1024)
gather_kernel(const float4* __restrict__ sorted,
              const int* __restrict__ starts,
              const int* __restrict__ mins,
              float* __restrict__ out) {
    __shared__ float tile[SLAB];
    int blk = blockIdx.x;
    int cb = blk / GRID_L;
    int ix = blk - cb * GRID_L;

    int minoffx = mins[0] + 64;           // abs-bin of the global min corner
    int minoffy = mins[1] + 64;
    int minoffz = mins[2] + 64;

    for (int t = threadIdx.x; t < SLAB; t += 1024) tile[t] = 0.0f;
    __syncthreads();

    const float4* pts = sorted + (size_t)cb * NPTS;
    const int* st = starts + cb * (NBINS + 1);

    #pragma unroll
    for (int pass = 0; pass < 2; ++pass) {
        int bin = ix - 2 + pass + minoffx;
        if (bin < 0 || bin >= NBINS) continue;
        int b0 = st[bin], b1 = st[bin + 1];
        for (int p = b0 + (int)threadIdx.x; p < b1; p += 1024) {
            float4 q = pts[p];
            int pack = __float_as_int(q.w);
            int py = (pack & 0xffff) - minoffy + 1;
            int pz = (pack >> 16) - minoffz + 1;
            float wx = pass ? (1.0f - q.x) : q.x;
            float wy0 = 1.0f - q.y, wy1 = q.y;
            float wz0 = 1.0f - q.z, wz1 = q.z;
            float* t0 = &tile[py * GRID_L + pz];
            atomicAdd(t0,              wx * wy0 * wz0);
            atomicAdd(t0 + 1,          wx * wy0 * wz1);
            atomicAdd(t0 + GRID_L,     wx * wy1 * wz0);
            atomicAdd(t0 + GRID_L + 1, wx * wy1 * wz1);
        }
    }
    __syncthreads();

    float* o = out + (size_t)cb * GRID_V + (size_t)ix * SLAB;
    for (int t = threadIdx.x; t < SLAB; t += 1024)
        __builtin_nontemporal_store(tile[t], &o[t]);
}

extern "C" void kernel_launch(void* const* d_in, const int* in_sizes, int n_in,
                              void* d_out, int out_size, void* d_ws, size_t ws_size,
                              hipStream_t stream) {
    const float* pred = (const float*)d_in[0];
    const float* gt   = (const float*)d_in[1];
    float* out = (float*)d_out;   // [2, BATCH, GRID_V]: pred grids then gt grids

    // workspace layout
    char* w = (char*)d_ws;
    int* mins   = (int*)w;                         // 3 ints
    int* counts = (int*)(w + 16);                  // NCB*NBINS
    int* starts = counts + NCB * NBINS;            // NCB*(NBINS+1)
    int* cursor = starts + NCB * (NBINS + 1);      // NCB*NBINS
    size_t off = 16 + sizeof(int) * (size_t)(NCB * NBINS + NCB * (NBINS + 1) + NCB * NBINS);
    off = (off + 15) & ~(size_t)15;
    float4* sorted = (float4*)(w + off);           // NCB*NPTS float4 = 16 MB

    hipMemsetAsync(mins, 0x7f, 3 * sizeof(int), stream);
    hipMemsetAsync(counts, 0, sizeof(int) * NCB * NBINS, stream);

    const int total2 = 2 * BATCH * NPTS;           // 1,048,576
    min_hist_kernel<<<total2 / 1024, 1024, 0, stream>>>(pred, gt, mins, counts);
    scan_kernel<<<1, 64, 0, stream>>>(counts, starts, cursor);
    reorder_kernel<<<(total2 + 255) / 256, 256, 0, stream>>>(pred, gt, cursor, sorted);
    gather_kernel<<<NCB * GRID_L, 1024, 0, stream>>>(sorted, starts, mins, out);
}